// Round 1
// 333.509 us; speedup vs baseline: 1.1773x; 1.1773x over previous
//
#include <hip/hip_runtime.h>
#include <cstdint>
#include <cstddef>

#define BS   8
#define C    256
#define C2   128
#define NPIX 4096

typedef unsigned short u16;
typedef unsigned int   u32;
typedef __bf16 bf16_t;
typedef bf16_t bf16x8 __attribute__((ext_vector_type(8)));
typedef float  f32x16 __attribute__((ext_vector_type(16)));

__device__ __forceinline__ u16 f2bf(float f) {
    union { float ff; u32 i; } x; x.ff = f;
    u32 r = x.i + 0x7fffu + ((x.i >> 16) & 1u);  // RNE
    return (u16)(r >> 16);
}

// split fp32 into hi/lo bf16 (truncation): hi+lo reconstructs f to ~2^-16 rel
__device__ __forceinline__ void split2(float f, u16& hi, u16& lo) {
    union { float ff; u32 i; } x; x.ff = f;
    hi = (u16)(x.i >> 16);
    union { u32 i; float ff; } h; h.i = x.i & 0xffff0000u;
    union { float ff; u32 i; } r; r.ff = f - h.ff;
    lo = (u16)(r.i >> 16);
}

__device__ __forceinline__ u32 pk2(u16 a, u16 b) { return (u32)a | ((u32)b << 16); }

// ---------------- W pre-split: fp32 -> hi/lo bf16 (same [o][c] layout) -----
__global__ __launch_bounds__(256)
void prep_w(const float* __restrict__ Wq, const float* __restrict__ Wk,
            const float* __restrict__ Wv,
            u16* __restrict__ qh, u16* __restrict__ ql,
            u16* __restrict__ kh, u16* __restrict__ kl,
            u16* __restrict__ vh, u16* __restrict__ vl) {
    const int z = blockIdx.y;                       // 0=q 1=k 2=v
    const int nelem = (z == 2) ? (C * C) : (C2 * C2);
    const int idx = (blockIdx.x * 256 + threadIdx.x) * 4;
    if (idx >= nelem) return;
    const float* src = (z == 0) ? Wq : (z == 1) ? Wk : Wv;
    u16* oh = (z == 0) ? qh : (z == 1) ? kh : vh;
    u16* ol = (z == 0) ? ql : (z == 1) ? kl : vl;
    const float4 v = *(const float4*)(src + idx);
    u16 h[4], l[4];
    split2(v.x, h[0], l[0]); split2(v.y, h[1], l[1]);
    split2(v.z, h[2], l[2]); split2(v.w, h[3], l[3]);
    *(uint2*)(oh + idx) = make_uint2(pk2(h[0], h[1]), pk2(h[2], h[3]));
    *(uint2*)(ol + idx) = make_uint2(pk2(l[0], l[1]), pk2(l[2], l[3]));
}

// ------------- Q/K projection via split-bf16 MFMA, out [b][n][128] ---------
// Block: 4 waves, o = 128 (wave w owns o-strip 32w..32w+31), n-tile = 64.
// A = W (hi/lo frags direct from L2-hot global). B = X staged+split+transposed
// into LDS layout [split][hs][n][8e] (sequential 16B/lane -> conflict-free).
// D = Wh*Xh + Wh*Xl + Wl*Xh  (fp32 accum; error ~2^-16 vs fp32 GEMM).
__global__ __launch_bounds__(256, 4)
void proj_qk(const u16* __restrict__ wh, const u16* __restrict__ wl, // [128][128]
             const float* __restrict__ bias,
             const float* __restrict__ x,        // [BS][128][4096] f32
             u16* __restrict__ out) {            // [BS][4096][128] bf16
    __shared__ __align__(16) u16 Xb[2][2][2][64][8]; // [dbuf][split][hs][n][e]
    const int t  = threadIdx.x;
    const int w  = t >> 6;
    const int li = t & 31;
    const int hs = (t >> 5) & 1;
    const int n0 = blockIdx.x * 64;
    const int b  = blockIdx.y;

    const int sn = t & 63;   // staging: n within tile
    const int c4 = t >> 6;   // staging: k-quad (4 consecutive c)
    const int sh = c4 >> 1, e0 = (c4 & 1) * 4;

    const float* xbase = x + (size_t)b * C2 * NPIX + n0 + sn;

    f32x16 acc[2];
    #pragma unroll
    for (int nt = 0; nt < 2; ++nt)
        #pragma unroll
        for (int e = 0; e < 16; ++e) acc[nt][e] = 0.f;

    // prologue stage ks=0 -> buf0
    {
        const float* xp = xbase + (size_t)(c4 * 4) * NPIX;
        const float f0 = xp[0], f1 = xp[NPIX], f2 = xp[2 * NPIX], f3 = xp[3 * NPIX];
        u16 h[4], lo[4];
        split2(f0, h[0], lo[0]); split2(f1, h[1], lo[1]);
        split2(f2, h[2], lo[2]); split2(f3, h[3], lo[3]);
        *(uint2*)&Xb[0][0][sh][sn][e0] = make_uint2(pk2(h[0], h[1]), pk2(h[2], h[3]));
        *(uint2*)&Xb[0][1][sh][sn][e0] = make_uint2(pk2(lo[0], lo[1]), pk2(lo[2], lo[3]));
    }
    __syncthreads();

    const size_t wrow = (size_t)(w * 32 + li) * C2;
    for (int ks = 0; ks < 8; ++ks) {
        const int db = ks & 1;
        if (ks < 7) {
            const float* xp = xbase + (size_t)((ks + 1) * 16 + c4 * 4) * NPIX;
            const float f0 = xp[0], f1 = xp[NPIX], f2 = xp[2 * NPIX], f3 = xp[3 * NPIX];
            u16 h[4], lo[4];
            split2(f0, h[0], lo[0]); split2(f1, h[1], lo[1]);
            split2(f2, h[2], lo[2]); split2(f3, h[3], lo[3]);
            *(uint2*)&Xb[db ^ 1][0][sh][sn][e0] = make_uint2(pk2(h[0], h[1]), pk2(h[2], h[3]));
            *(uint2*)&Xb[db ^ 1][1][sh][sn][e0] = make_uint2(pk2(lo[0], lo[1]), pk2(lo[2], lo[3]));
        }
        const int ko = ks * 16 + hs * 8;
        const bf16x8 ah = *(const bf16x8*)(wh + wrow + ko);
        const bf16x8 al = *(const bf16x8*)(wl + wrow + ko);
        #pragma unroll
        for (int nt = 0; nt < 2; ++nt) {
            const bf16x8 bh = *(const bf16x8*)&Xb[db][0][hs][nt * 32 + li][0];
            const bf16x8 bl = *(const bf16x8*)&Xb[db][1][hs][nt * 32 + li][0];
            acc[nt] = __builtin_amdgcn_mfma_f32_32x32x16_bf16(ah, bh, acc[nt], 0, 0, 0);
            acc[nt] = __builtin_amdgcn_mfma_f32_32x32x16_bf16(ah, bl, acc[nt], 0, 0, 0);
            acc[nt] = __builtin_amdgcn_mfma_f32_32x32x16_bf16(al, bh, acc[nt], 0, 0, 0);
        }
        __syncthreads();
    }

    // D: col = n (lane&31), row = o = (r&3)+8*(r>>2)+4*hs  -> pack 4 consecutive o
    #pragma unroll
    for (int nt = 0; nt < 2; ++nt) {
        const int n = n0 + nt * 32 + li;
        u16* op = out + ((size_t)b * NPIX + n) * C2 + w * 32;
        #pragma unroll
        for (int g = 0; g < 4; ++g) {
            const int ob = 8 * g + 4 * hs;
            u16 p[4];
            #pragma unroll
            for (int j = 0; j < 4; ++j)
                p[j] = f2bf(acc[nt][g * 4 + j] + bias[w * 32 + ob + j]);
            *(uint2*)(op + ob) = make_uint2(pk2(p[0], p[1]), pk2(p[2], p[3]));
        }
    }
}

// ------------- V projection via split-bf16 MFMA, out [b][o][n] -------------
// Block: n = 128 (wave w owns n-strip), o = 128 (4 MFMA col-tiles).
// A = X^T (staged+split LDS), B = W (hi/lo pre-split, staged to LDS shared by
// all 4 waves). Layouts [split][hs][row][8e] -> conflict-free b128.
__global__ __launch_bounds__(256, 2)
void proj_v(const u16* __restrict__ wh, const u16* __restrict__ wl, // [256][256]
            const float* __restrict__ bias,
            const float* __restrict__ x,        // [BS][256][4096] f32
            u16* __restrict__ out) {            // [BS][256][4096] bf16
    __shared__ __align__(16) u16 Xs[2][2][2][128][8]; // [dbuf][split][hs][n][e]
    __shared__ __align__(16) u16 Ws[2][2][2][128][8]; // [dbuf][split][hs][o][e]
    const int t  = threadIdx.x;
    const int w  = t >> 6;
    const int li = t & 31;
    const int hs = (t >> 5) & 1;
    const int n0 = blockIdx.x * 128;
    const int o0 = blockIdx.y * 128;
    const int b  = blockIdx.z;

    const int sn = t & 127;       // X staging: n
    const int sc = t >> 7;        // X staging: hs chunk (8 consecutive c)
    const int so = t >> 1;        // W staging: o 0..127
    const int sh2 = t & 1;        // W staging: hs

    const float* xbase = x + (size_t)b * C * NPIX + n0 + sn;
    const u16* whb = wh + (size_t)(o0 + so) * C + sh2 * 8;
    const u16* wlb = wl + (size_t)(o0 + so) * C + sh2 * 8;

    f32x16 acc[4];
    #pragma unroll
    for (int ot = 0; ot < 4; ++ot)
        #pragma unroll
        for (int e = 0; e < 16; ++e) acc[ot][e] = 0.f;

    // prologue stage ks=0
    {
        const float* xp = xbase + (size_t)(sc * 8) * NPIX;
        u16 h[8], lo[8];
        #pragma unroll
        for (int j = 0; j < 8; ++j) split2(xp[(size_t)j * NPIX], h[j], lo[j]);
        *(uint4*)&Xs[0][0][sc][sn][0] =
            make_uint4(pk2(h[0], h[1]), pk2(h[2], h[3]), pk2(h[4], h[5]), pk2(h[6], h[7]));
        *(uint4*)&Xs[0][1][sc][sn][0] =
            make_uint4(pk2(lo[0], lo[1]), pk2(lo[2], lo[3]), pk2(lo[4], lo[5]), pk2(lo[6], lo[7]));
        *(uint4*)&Ws[0][0][sh2][so][0] = *(const uint4*)(whb);
        *(uint4*)&Ws[0][1][sh2][so][0] = *(const uint4*)(wlb);
    }
    __syncthreads();

    for (int ks = 0; ks < 16; ++ks) {
        const int db = ks & 1;
        if (ks < 15) {
            const float* xp = xbase + (size_t)((ks + 1) * 16 + sc * 8) * NPIX;
            u16 h[8], lo[8];
            #pragma unroll
            for (int j = 0; j < 8; ++j) split2(xp[(size_t)j * NPIX], h[j], lo[j]);
            *(uint4*)&Xs[db ^ 1][0][sc][sn][0] =
                make_uint4(pk2(h[0], h[1]), pk2(h[2], h[3]), pk2(h[4], h[5]), pk2(h[6], h[7]));
            *(uint4*)&Xs[db ^ 1][1][sc][sn][0] =
                make_uint4(pk2(lo[0], lo[1]), pk2(lo[2], lo[3]), pk2(lo[4], lo[5]), pk2(lo[6], lo[7]));
            *(uint4*)&Ws[db ^ 1][0][sh2][so][0] = *(const uint4*)(whb + (ks + 1) * 16);
            *(uint4*)&Ws[db ^ 1][1][sh2][so][0] = *(const uint4*)(wlb + (ks + 1) * 16);
        }
        const bf16x8 xh = *(const bf16x8*)&Xs[db][0][hs][w * 32 + li][0];
        const bf16x8 xl = *(const bf16x8*)&Xs[db][1][hs][w * 32 + li][0];
        #pragma unroll
        for (int ot = 0; ot < 4; ++ot) {
            const bf16x8 bh = *(const bf16x8*)&Ws[db][0][hs][ot * 32 + li][0];
            const bf16x8 bl = *(const bf16x8*)&Ws[db][1][hs][ot * 32 + li][0];
            acc[ot] = __builtin_amdgcn_mfma_f32_32x32x16_bf16(xh, bh, acc[ot], 0, 0, 0);
            acc[ot] = __builtin_amdgcn_mfma_f32_32x32x16_bf16(xh, bl, acc[ot], 0, 0, 0);
            acc[ot] = __builtin_amdgcn_mfma_f32_32x32x16_bf16(xl, bh, acc[ot], 0, 0, 0);
        }
        __syncthreads();
    }

    // D: col = o (lane&31), row = n = (r&3)+8*(r>>2)+4*hs -> pack 4 consecutive n
    #pragma unroll
    for (int ot = 0; ot < 4; ++ot) {
        const int o = o0 + ot * 32 + li;
        const float bb = bias[o];
        u16* op = out + ((size_t)b * C + o) * NPIX + n0 + w * 32;
        #pragma unroll
        for (int g = 0; g < 4; ++g) {
            u16 p[4];
            #pragma unroll
            for (int j = 0; j < 4; ++j) p[j] = f2bf(acc[ot][g * 4 + j] + bb);
            *(uint2*)(op + 8 * g + 4 * hs) = make_uint2(pk2(p[0], p[1]), pk2(p[2], p[3]));
        }
    }
}

// ----------------------------- MFMA attention v3 ---------------------------
// (unchanged from previous round)
struct SR { uint4 k[2]; uint4 v[4]; };

__device__ __forceinline__ void stg_load(const u16* __restrict__ kg,
                                         const u16* __restrict__ vg,
                                         int jt, int t, SR& R) {
    const u16* kp = kg + (size_t)jt * 32 * 128;
    #pragma unroll
    for (int q = 0; q < 2; ++q)
        R.k[q] = *(const uint4*)(kp + (size_t)(t + 256 * q) * 8);
    const u16* vp = vg + jt * 32 + (t & 3) * 8;
    #pragma unroll
    for (int q = 0; q < 4; ++q)
        R.v[q] = *(const uint4*)(vp + (size_t)((t >> 2) + 64 * q) * NPIX);
}

__device__ __forceinline__ void stg_write(u16* __restrict__ kb, u16* __restrict__ vb,
                                          int t, const SR& R) {
    #pragma unroll
    for (int q = 0; q < 2; ++q) {
        const int idx = t + 256 * q;
        const int row = idx >> 4;
        const int ch  = (idx & 15) ^ (row & 15);
        *(uint4*)(kb + row * 128 + ch * 8) = R.k[q];
    }
    #pragma unroll
    for (int q = 0; q < 4; ++q) {
        const int c   = (t >> 2) + 64 * q;
        const int rc  = c >> 1;
        const int q8  = (c & 1) * 8 + (t & 3) * 2;
        const int x   = rc & 15;
        const int ch0 = q8 ^ x;
        const int ch1 = (q8 + 1) ^ x;
        *(uint2*)(vb + rc * 64 + ch0 * 4) = make_uint2(R.v[q].x, R.v[q].y);
        *(uint2*)(vb + rc * 64 + ch1 * 4) = make_uint2(R.v[q].z, R.v[q].w);
    }
}

__global__ __launch_bounds__(256, 2)
void attn_mfma3(const u16* __restrict__ qt,   // [BS][NPIX][C2]
                const u16* __restrict__ kt,   // [BS][NPIX][C2]
                const u16* __restrict__ vn,   // [BS][C][NPIX]
                float* __restrict__ opart0,   // partial O, j-half 0 (fuse slot)
                float* __restrict__ opart1,   // partial O, j-half 1 (out slot)
                float* __restrict__ sbuf) {   // [2][BS][NPIX] partial sums
    __shared__ u16 Kb[2][32 * 128];
    __shared__ u16 Vb[2][128 * 64];

    const int t  = threadIdx.x;
    const int w  = t >> 6;
    const int li = t & 31;
    const int hs = (t >> 5) & 1;

    const int b  = blockIdx.x & 7;                 // batch <-> XCD affinity
    const int it = (blockIdx.x >> 3) & 31;
    const int h  = blockIdx.x >> 8;                // j-half
    const int i0 = it * 128;
    const int iw = i0 + w * 32 + li;
    const int j0 = h * 2048;

    bf16x8 qf[8];
    {
        const u16* qp = qt + ((size_t)b * NPIX + iw) * C2 + hs * 8;
        #pragma unroll
        for (int ct = 0; ct < 8; ++ct) qf[ct] = *(const bf16x8*)(qp + ct * 16);
    }

    f32x16 oacc[8];
    #pragma unroll
    for (int ct = 0; ct < 8; ++ct)
        #pragma unroll
        for (int e = 0; e < 16; ++e) oacc[ct][e] = 0.f;

    const u16* ktb = kt + ((size_t)b * NPIX + j0) * C2;
    const u16* vnb = vn + (size_t)b * C * NPIX + j0;

    SR R;
    stg_load(ktb, vnb, 0, t, R);
    stg_write(&Kb[0][0], &Vb[0][0], t, R);
    stg_load(ktb, vnb, 1, t, R);
    __syncthreads();

    float ssl = 0.f;
    for (int itr = 0; itr < 64; ++itr) {
        const int cur = itr & 1;
        if (itr < 63) {
            stg_write(&Kb[cur ^ 1][0], &Vb[cur ^ 1][0], t, R);
            if (itr < 62) stg_load(ktb, vnb, itr + 2, t, R);
        }
        const u16* kb = &Kb[cur][0];
        const u16* vb = &Vb[cur][0];

        f32x16 s;
        #pragma unroll
        for (int e = 0; e < 16; ++e) s[e] = 0.f;
        {
            const int xr = li & 15;
            #pragma unroll
            for (int ct = 0; ct < 8; ++ct) {
                const int ch = (ct * 2 + hs) ^ xr;
                const bf16x8 kf = *(const bf16x8*)(kb + li * 128 + ch * 8);
                s = __builtin_amdgcn_mfma_f32_32x32x16_bf16(kf, qf[ct], s, 0, 0, 0);
            }
        }

        u32 pk[8];
        #pragma unroll
        for (int n = 0; n < 8; ++n) {
            const float p0 = __expf(s[2 * n]);
            const float p1 = __expf(s[2 * n + 1]);
            ssl += p0 + p1;
            pk[n] = (u32)f2bf(p0) | ((u32)f2bf(p1) << 16);
        }

        bf16x8 pf[2];
        #pragma unroll
        for (int seg = 0; seg < 2; ++seg) {
            const u32 A0 = pk[4 * seg + 0], A1 = pk[4 * seg + 1];
            const u32 A2 = pk[4 * seg + 2], A3 = pk[4 * seg + 3];
            const u32 own0 = hs ? A2 : A0, own1 = hs ? A3 : A1;
            const u32 snd0 = hs ? A0 : A2, snd1 = hs ? A1 : A3;
            const u32 rcv0 = (u32)__shfl_xor((int)snd0, 32, 64);
            const u32 rcv1 = (u32)__shfl_xor((int)snd1, 32, 64);
            union { u32 u[4]; bf16x8 v; } bb;
            bb.u[0] = hs ? rcv0 : own0;
            bb.u[1] = hs ? rcv1 : own1;
            bb.u[2] = hs ? own0 : rcv0;
            bb.u[3] = hs ? own1 : rcv1;
            pf[seg] = bb.v;
        }

        #pragma unroll
        for (int ct = 0; ct < 8; ++ct) {
            const int c  = ct * 32 + li;
            const int rc = c >> 1;
            const int x  = rc & 15;
            const u16* vr = vb + rc * 64;
            const int cb = (c & 1) * 8 + hs * 2;
            #pragma unroll
            for (int seg = 0; seg < 2; ++seg) {
                const int q8  = cb + seg * 4;
                const int ch0 = q8 ^ x;
                const int ch1 = (q8 + 1) ^ x;
                union { uint2 g[2]; bf16x8 v8; } u;
                u.g[0] = *(const uint2*)(vr + ch0 * 4);
                u.g[1] = *(const uint2*)(vr + ch1 * 4);
                oacc[ct] = __builtin_amdgcn_mfma_f32_32x32x16_bf16(u.v8, pf[seg], oacc[ct], 0, 0, 0);
            }
        }
        __syncthreads();
    }

    ssl += __shfl_xor(ssl, 32, 64);
    if (hs == 0) sbuf[((size_t)h * BS + b) * NPIX + iw] = ssl;

    float* op = h ? opart1 : opart0;
    #pragma unroll
    for (int ct = 0; ct < 8; ++ct) {
        #pragma unroll
        for (int r = 0; r < 16; ++r) {
            const int c = ct * 32 + (r & 3) + 8 * (r >> 2) + 4 * hs;
            op[((size_t)b * C + c) * NPIX + iw] = oacc[ct][r];
        }
    }
}

// ---- merge: out = (O1+O2)/(s1+s2); fuse = out*motion -----------------------
__global__ __launch_bounds__(256)
void attn_merge(float* __restrict__ fuse,    // in: O1 partial, out: fuse_out
                float* __restrict__ outp,    // in: O2 partial, out: out
                const float* __restrict__ motion,
                const float* __restrict__ sbuf) {
    const size_t idx = ((size_t)blockIdx.x * 256 + threadIdx.x) * 4;
    const int n = (int)(idx & (NPIX - 1));
    const int b = (int)(idx >> 20);
    const float4 o1 = *(const float4*)(fuse + idx);
    const float4 o2 = *(const float4*)(outp + idx);
    const float4 sa = *(const float4*)(sbuf + (size_t)b * NPIX + n);
    const float4 sb = *(const float4*)(sbuf + (size_t)(BS + b) * NPIX + n);
    float4 o;
    o.x = (o1.x + o2.x) / (sa.x + sb.x);
    o.y = (o1.y + o2.y) / (sa.y + sb.y);
    o.z = (o1.z + o2.z) / (sa.z + sb.z);
    o.w = (o1.w + o2.w) / (sa.w + sb.w);
    const float4 mv = *(const float4*)(motion + idx);
    *(float4*)(outp + idx) = o;
    *(float4*)(fuse + idx) = make_float4(o.x * mv.x, o.y * mv.y, o.z * mv.z, o.w * mv.w);
}

extern "C" void kernel_launch(void* const* d_in, const int* in_sizes, int n_in,
                              void* d_out, int out_size, void* d_ws, size_t ws_size,
                              hipStream_t stream) {
    const float* a1     = (const float*)d_in[0];  // appearance_1 -> k
    const float* a2     = (const float*)d_in[1];  // appearance_2 -> q
    const float* motion = (const float*)d_in[2];  // -> v, and fuse multiplier
    const float* Wq = (const float*)d_in[3];
    const float* bq = (const float*)d_in[4];
    const float* Wk = (const float*)d_in[5];
    const float* bk = (const float*)d_in[6];
    const float* Wv = (const float*)d_in[7];
    const float* bv = (const float*)d_in[8];

    float* outp = (float*)d_out;  // [fuse_out | out]
    float* slot0 = outp;                              // fuse slot / O1 partial
    float* slot1 = outp + (size_t)BS * C * NPIX;      // out slot  / O2 partial

    // workspace: QT (8MB) | KT (8MB) | V (16MB) | sbuf (256KB) | W splits (384KB)
    u16* qws = (u16*)d_ws;
    u16* kws = qws + (size_t)BS * C2 * NPIX;
    u16* vws = kws + (size_t)BS * C2 * NPIX;
    float* sbuf = (float*)(vws + (size_t)BS * C * NPIX);
    u16* wqh = (u16*)(sbuf + (size_t)2 * BS * NPIX);
    u16* wql = wqh + C2 * C2;
    u16* wkh = wql + C2 * C2;
    u16* wkl = wkh + C2 * C2;
    u16* wvh = wkl + C2 * C2;
    u16* wvl = wvh + C * C;

    const dim3 blk(256);
    prep_w<<<dim3(64, 3), blk, 0, stream>>>(Wq, Wk, Wv, wqh, wql, wkh, wkl, wvh, wvl);
    proj_qk<<<dim3(NPIX / 64, BS), blk, 0, stream>>>(wqh, wql, bq, a2, qws);
    proj_qk<<<dim3(NPIX / 64, BS), blk, 0, stream>>>(wkh, wkl, bk, a1, kws);
    proj_v<<<dim3(NPIX / 128, 2, BS), blk, 0, stream>>>(wvh, wvl, bv, motion, vws);

    attn_mfma3<<<dim3(512), blk, 0, stream>>>(qws, kws, vws, slot0, slot1, sbuf);

    attn_merge<<<dim3((BS * C * NPIX) / 1024), blk, 0, stream>>>(
        slot0, slot1, motion, sbuf);
}

// Round 2
// 329.687 us; speedup vs baseline: 1.1910x; 1.0116x over previous
//
#include <hip/hip_runtime.h>
#include <cstdint>
#include <cstddef>

#define BS   8
#define C    256
#define C2   128
#define NPIX 4096

typedef unsigned short u16;
typedef unsigned int   u32;
typedef __bf16 bf16_t;
typedef bf16_t bf16x8 __attribute__((ext_vector_type(8)));
typedef float  f32x16 __attribute__((ext_vector_type(16)));

__device__ __forceinline__ u16 f2bf(float f) {
    union { float ff; u32 i; } x; x.ff = f;
    u32 r = x.i + 0x7fffu + ((x.i >> 16) & 1u);  // RNE
    return (u16)(r >> 16);
}

// split fp32 into hi/lo bf16 (truncation): hi+lo reconstructs f to ~2^-16 rel
__device__ __forceinline__ void split2(float f, u16& hi, u16& lo) {
    union { float ff; u32 i; } x; x.ff = f;
    hi = (u16)(x.i >> 16);
    union { u32 i; float ff; } h; h.i = x.i & 0xffff0000u;
    union { float ff; u32 i; } r; r.ff = f - h.ff;
    lo = (u16)(r.i >> 16);
}

__device__ __forceinline__ u32 pk2(u16 a, u16 b) { return (u32)a | ((u32)b << 16); }

// ---------------- W pre-split into FRAGMENT-MAJOR layout --------------------
// W[o][c] fp32  ->  W2[c8][o][8] split bf16 (hi,lo), c8 = c>>3.
// Fragment load in proj kernels becomes lane-contiguous (1KB/instr from L2).
__global__ __launch_bounds__(256)
void prep_w(const float* __restrict__ Wq, const float* __restrict__ Wk,
            const float* __restrict__ Wv,
            u16* __restrict__ qh, u16* __restrict__ ql,
            u16* __restrict__ kh, u16* __restrict__ kl,
            u16* __restrict__ vh, u16* __restrict__ vl) {
    const int z = blockIdx.y;                       // 0=q 1=k 2=v
    const int O = (z == 2) ? C : C2;                // O == CIN for all three
    const int npair = O * O / 8;
    const int idx = blockIdx.x * 256 + threadIdx.x;
    if (idx >= npair) return;
    const int o  = idx & (O - 1);
    const int c8 = idx >> ((z == 2) ? 8 : 7);
    const float* src = (z == 0) ? Wq : (z == 1) ? Wk : Wv;
    u16* oh = (z == 0) ? qh : (z == 1) ? kh : vh;
    u16* ol = (z == 0) ? ql : (z == 1) ? kl : vl;
    const float4 f0 = *(const float4*)(src + (size_t)o * O + c8 * 8);
    const float4 f1 = *(const float4*)(src + (size_t)o * O + c8 * 8 + 4);
    u16 h[8], l[8];
    split2(f0.x, h[0], l[0]); split2(f0.y, h[1], l[1]);
    split2(f0.z, h[2], l[2]); split2(f0.w, h[3], l[3]);
    split2(f1.x, h[4], l[4]); split2(f1.y, h[5], l[5]);
    split2(f1.z, h[6], l[6]); split2(f1.w, h[7], l[7]);
    *(uint4*)(oh + (size_t)idx * 8) =
        make_uint4(pk2(h[0], h[1]), pk2(h[2], h[3]), pk2(h[4], h[5]), pk2(h[6], h[7]));
    *(uint4*)(ol + (size_t)idx * 8) =
        make_uint4(pk2(l[0], l[1]), pk2(l[2], l[3]), pk2(l[4], l[5]), pk2(l[6], l[7]));
}

// ------------- Q & K projection (fused, z picks q/k), out [b][n][128] ------
// One-shot staging: full K=128 x 64n X-tile split into LDS (32KB), ONE barrier,
// then pure ds_read_b128 + MFMA (no barriers, no per-step vmcnt stalls).
// D = mfma(A=X, B=W): col = o = lane -> contiguous u16 stores.
__global__ __launch_bounds__(256, 2)
void proj_qk2(const u16* __restrict__ qh2, const u16* __restrict__ ql2,
              const float* __restrict__ bq,
              const u16* __restrict__ kh2, const u16* __restrict__ kl2,
              const float* __restrict__ bk,
              const float* __restrict__ a2, const float* __restrict__ a1,
              u16* __restrict__ qout, u16* __restrict__ kout) {
    __shared__ __align__(16) u16 Xb[2][16][64][8];   // [split][c8][n][e] 32KB
    const int t  = threadIdx.x;
    const int w  = t >> 6;
    const int li = t & 31;
    const int hs = (t >> 5) & 1;
    const int n0 = blockIdx.x * 64;
    const int b  = blockIdx.y;
    const int z  = blockIdx.z;

    const u16* wh  = z ? kh2 : qh2;
    const u16* wl  = z ? kl2 : ql2;
    const float* bias = z ? bk : bq;
    const float* x = z ? a1 : a2;
    u16* out = z ? kout : qout;

    // ---- stage: 32 coalesced scalar loads/thread, split, 8 uint4 LDS writes
    {
        const int sn = t & 63;
        const float* xb = x + (size_t)b * C2 * NPIX + n0 + sn;
        float xv[4][8];
        #pragma unroll
        for (int q = 0; q < 4; ++q) {
            const int c0 = (q * 4 + w) * 8;
            #pragma unroll
            for (int j = 0; j < 8; ++j) xv[q][j] = xb[(size_t)(c0 + j) * NPIX];
        }
        #pragma unroll
        for (int q = 0; q < 4; ++q) {
            u16 h[8], l[8];
            #pragma unroll
            for (int j = 0; j < 8; ++j) split2(xv[q][j], h[j], l[j]);
            *(uint4*)&Xb[0][q * 4 + w][sn][0] =
                make_uint4(pk2(h[0], h[1]), pk2(h[2], h[3]), pk2(h[4], h[5]), pk2(h[6], h[7]));
            *(uint4*)&Xb[1][q * 4 + w][sn][0] =
                make_uint4(pk2(l[0], l[1]), pk2(l[2], l[3]), pk2(l[4], l[5]), pk2(l[6], l[7]));
        }
    }
    __syncthreads();

    f32x16 acc[2];
    #pragma unroll
    for (int nt = 0; nt < 2; ++nt)
        #pragma unroll
        for (int e = 0; e < 16; ++e) acc[nt][e] = 0.f;

    const int ob = w * 32 + li;   // lane's output channel (D col)
    #pragma unroll
    for (int ks = 0; ks < 8; ++ks) {
        const int c8 = ks * 2 + hs;
        const bf16x8 bh = *(const bf16x8*)(wh + ((size_t)c8 * C2 + ob) * 8);
        const bf16x8 bl = *(const bf16x8*)(wl + ((size_t)c8 * C2 + ob) * 8);
        #pragma unroll
        for (int nt = 0; nt < 2; ++nt) {
            const bf16x8 ah = *(const bf16x8*)&Xb[0][c8][nt * 32 + li][0];
            const bf16x8 al = *(const bf16x8*)&Xb[1][c8][nt * 32 + li][0];
            acc[nt] = __builtin_amdgcn_mfma_f32_32x32x16_bf16(ah, bh, acc[nt], 0, 0, 0);
            acc[nt] = __builtin_amdgcn_mfma_f32_32x32x16_bf16(ah, bl, acc[nt], 0, 0, 0);
            acc[nt] = __builtin_amdgcn_mfma_f32_32x32x16_bf16(al, bh, acc[nt], 0, 0, 0);
        }
    }

    // D: col = o = lane, row = n = (r&3)+8*(r>>2)+4*hs (+ nt*32)
    const float bb = bias[ob];
    #pragma unroll
    for (int nt = 0; nt < 2; ++nt)
        #pragma unroll
        for (int r = 0; r < 16; ++r) {
            const int n = n0 + nt * 32 + (r & 3) + 8 * (r >> 2) + 4 * hs;
            out[((size_t)b * NPIX + n) * C2 + ob] = f2bf(acc[nt][r] + bb);
        }
}

// ------------- V projection, out [b][o][n] ---------------------------------
// Full K=256 x 64n X-tile split into LDS (64KB), ONE barrier, then MFMA.
// D = mfma(A=W, B=X): col = n = lane -> contiguous u16 stores.
__global__ __launch_bounds__(256, 2)
void proj_v2(const u16* __restrict__ wh, const u16* __restrict__ wl, // [32][256][8]
             const float* __restrict__ bias,
             const float* __restrict__ x,        // [BS][256][4096] f32
             u16* __restrict__ out) {            // [BS][256][4096] bf16
    __shared__ __align__(16) u16 Xb[2][32][64][8];   // 64KB
    const int t  = threadIdx.x;
    const int w  = t >> 6;
    const int li = t & 31;
    const int hs = (t >> 5) & 1;
    const int n0 = blockIdx.x * 64;
    const int b  = blockIdx.y;

    // ---- stage: 64 coalesced scalar loads/thread in 2 rounds
    {
        const int sn = t & 63;
        const float* xb = x + (size_t)b * C * NPIX + n0 + sn;
        #pragma unroll
        for (int rr = 0; rr < 2; ++rr) {
            float xv[4][8];
            #pragma unroll
            for (int q = 0; q < 4; ++q) {
                const int c0 = ((rr * 4 + q) * 4 + w) * 8;
                #pragma unroll
                for (int j = 0; j < 8; ++j) xv[q][j] = xb[(size_t)(c0 + j) * NPIX];
            }
            #pragma unroll
            for (int q = 0; q < 4; ++q) {
                u16 h[8], l[8];
                #pragma unroll
                for (int j = 0; j < 8; ++j) split2(xv[q][j], h[j], l[j]);
                const int c8 = (rr * 4 + q) * 4 + w;
                *(uint4*)&Xb[0][c8][sn][0] =
                    make_uint4(pk2(h[0], h[1]), pk2(h[2], h[3]), pk2(h[4], h[5]), pk2(h[6], h[7]));
                *(uint4*)&Xb[1][c8][sn][0] =
                    make_uint4(pk2(l[0], l[1]), pk2(l[2], l[3]), pk2(l[4], l[5]), pk2(l[6], l[7]));
            }
        }
    }
    __syncthreads();

    f32x16 acc[2][2];   // [ot][nt]
    #pragma unroll
    for (int ot = 0; ot < 2; ++ot)
        #pragma unroll
        for (int nt = 0; nt < 2; ++nt)
            #pragma unroll
            for (int e = 0; e < 16; ++e) acc[ot][nt][e] = 0.f;

    #pragma unroll
    for (int ks = 0; ks < 16; ++ks) {
        const int c8 = ks * 2 + hs;
        bf16x8 ah[2], al[2], xh[2], xl[2];
        #pragma unroll
        for (int ot = 0; ot < 2; ++ot) {
            const int o = w * 64 + ot * 32 + li;
            ah[ot] = *(const bf16x8*)(wh + ((size_t)c8 * C + o) * 8);
            al[ot] = *(const bf16x8*)(wl + ((size_t)c8 * C + o) * 8);
        }
        #pragma unroll
        for (int nt = 0; nt < 2; ++nt) {
            xh[nt] = *(const bf16x8*)&Xb[0][c8][nt * 32 + li][0];
            xl[nt] = *(const bf16x8*)&Xb[1][c8][nt * 32 + li][0];
        }
        #pragma unroll
        for (int ot = 0; ot < 2; ++ot)
            #pragma unroll
            for (int nt = 0; nt < 2; ++nt) {
                acc[ot][nt] = __builtin_amdgcn_mfma_f32_32x32x16_bf16(ah[ot], xh[nt], acc[ot][nt], 0, 0, 0);
                acc[ot][nt] = __builtin_amdgcn_mfma_f32_32x32x16_bf16(ah[ot], xl[nt], acc[ot][nt], 0, 0, 0);
                acc[ot][nt] = __builtin_amdgcn_mfma_f32_32x32x16_bf16(al[ot], xh[nt], acc[ot][nt], 0, 0, 0);
            }
    }

    // D: col = n = lane, row = o = (r&3)+8*(r>>2)+4*hs (+ ot*32 + w*64)
    #pragma unroll
    for (int ot = 0; ot < 2; ++ot)
        #pragma unroll
        for (int nt = 0; nt < 2; ++nt)
            #pragma unroll
            for (int g = 0; g < 4; ++g) {
                const int orow = w * 64 + ot * 32 + 8 * g + 4 * hs;
                const float4 b4 = *(const float4*)&bias[orow];
                const size_t base = ((size_t)b * C + orow) * NPIX + n0 + nt * 32 + li;
                out[base]            = f2bf(acc[ot][nt][g * 4 + 0] + b4.x);
                out[base + NPIX]     = f2bf(acc[ot][nt][g * 4 + 1] + b4.y);
                out[base + 2 * NPIX] = f2bf(acc[ot][nt][g * 4 + 2] + b4.z);
                out[base + 3 * NPIX] = f2bf(acc[ot][nt][g * 4 + 3] + b4.w);
            }
}

// ----------------------------- MFMA attention v3 ---------------------------
// (unchanged)
struct SR { uint4 k[2]; uint4 v[4]; };

__device__ __forceinline__ void stg_load(const u16* __restrict__ kg,
                                         const u16* __restrict__ vg,
                                         int jt, int t, SR& R) {
    const u16* kp = kg + (size_t)jt * 32 * 128;
    #pragma unroll
    for (int q = 0; q < 2; ++q)
        R.k[q] = *(const uint4*)(kp + (size_t)(t + 256 * q) * 8);
    const u16* vp = vg + jt * 32 + (t & 3) * 8;
    #pragma unroll
    for (int q = 0; q < 4; ++q)
        R.v[q] = *(const uint4*)(vp + (size_t)((t >> 2) + 64 * q) * NPIX);
}

__device__ __forceinline__ void stg_write(u16* __restrict__ kb, u16* __restrict__ vb,
                                          int t, const SR& R) {
    #pragma unroll
    for (int q = 0; q < 2; ++q) {
        const int idx = t + 256 * q;
        const int row = idx >> 4;
        const int ch  = (idx & 15) ^ (row & 15);
        *(uint4*)(kb + row * 128 + ch * 8) = R.k[q];
    }
    #pragma unroll
    for (int q = 0; q < 4; ++q) {
        const int c   = (t >> 2) + 64 * q;
        const int rc  = c >> 1;
        const int q8  = (c & 1) * 8 + (t & 3) * 2;
        const int x   = rc & 15;
        const int ch0 = q8 ^ x;
        const int ch1 = (q8 + 1) ^ x;
        *(uint2*)(vb + rc * 64 + ch0 * 4) = make_uint2(R.v[q].x, R.v[q].y);
        *(uint2*)(vb + rc * 64 + ch1 * 4) = make_uint2(R.v[q].z, R.v[q].w);
    }
}

__global__ __launch_bounds__(256, 2)
void attn_mfma3(const u16* __restrict__ qt,   // [BS][NPIX][C2]
                const u16* __restrict__ kt,   // [BS][NPIX][C2]
                const u16* __restrict__ vn,   // [BS][C][NPIX]
                float* __restrict__ opart0,   // partial O, j-half 0 (fuse slot)
                float* __restrict__ opart1,   // partial O, j-half 1 (out slot)
                float* __restrict__ sbuf) {   // [2][BS][NPIX] partial sums
    __shared__ u16 Kb[2][32 * 128];
    __shared__ u16 Vb[2][128 * 64];

    const int t  = threadIdx.x;
    const int w  = t >> 6;
    const int li = t & 31;
    const int hs = (t >> 5) & 1;

    const int b  = blockIdx.x & 7;                 // batch <-> XCD affinity
    const int it = (blockIdx.x >> 3) & 31;
    const int h  = blockIdx.x >> 8;                // j-half
    const int i0 = it * 128;
    const int iw = i0 + w * 32 + li;
    const int j0 = h * 2048;

    bf16x8 qf[8];
    {
        const u16* qp = qt + ((size_t)b * NPIX + iw) * C2 + hs * 8;
        #pragma unroll
        for (int ct = 0; ct < 8; ++ct) qf[ct] = *(const bf16x8*)(qp + ct * 16);
    }

    f32x16 oacc[8];
    #pragma unroll
    for (int ct = 0; ct < 8; ++ct)
        #pragma unroll
        for (int e = 0; e < 16; ++e) oacc[ct][e] = 0.f;

    const u16* ktb = kt + ((size_t)b * NPIX + j0) * C2;
    const u16* vnb = vn + (size_t)b * C * NPIX + j0;

    SR R;
    stg_load(ktb, vnb, 0, t, R);
    stg_write(&Kb[0][0], &Vb[0][0], t, R);
    stg_load(ktb, vnb, 1, t, R);
    __syncthreads();

    float ssl = 0.f;
    for (int itr = 0; itr < 64; ++itr) {
        const int cur = itr & 1;
        if (itr < 63) {
            stg_write(&Kb[cur ^ 1][0], &Vb[cur ^ 1][0], t, R);
            if (itr < 62) stg_load(ktb, vnb, itr + 2, t, R);
        }
        const u16* kb = &Kb[cur][0];
        const u16* vb = &Vb[cur][0];

        f32x16 s;
        #pragma unroll
        for (int e = 0; e < 16; ++e) s[e] = 0.f;
        {
            const int xr = li & 15;
            #pragma unroll
            for (int ct = 0; ct < 8; ++ct) {
                const int ch = (ct * 2 + hs) ^ xr;
                const bf16x8 kf = *(const bf16x8*)(kb + li * 128 + ch * 8);
                s = __builtin_amdgcn_mfma_f32_32x32x16_bf16(kf, qf[ct], s, 0, 0, 0);
            }
        }

        u32 pk[8];
        #pragma unroll
        for (int n = 0; n < 8; ++n) {
            const float p0 = __expf(s[2 * n]);
            const float p1 = __expf(s[2 * n + 1]);
            ssl += p0 + p1;
            pk[n] = (u32)f2bf(p0) | ((u32)f2bf(p1) << 16);
        }

        bf16x8 pf[2];
        #pragma unroll
        for (int seg = 0; seg < 2; ++seg) {
            const u32 A0 = pk[4 * seg + 0], A1 = pk[4 * seg + 1];
            const u32 A2 = pk[4 * seg + 2], A3 = pk[4 * seg + 3];
            const u32 own0 = hs ? A2 : A0, own1 = hs ? A3 : A1;
            const u32 snd0 = hs ? A0 : A2, snd1 = hs ? A1 : A3;
            const u32 rcv0 = (u32)__shfl_xor((int)snd0, 32, 64);
            const u32 rcv1 = (u32)__shfl_xor((int)snd1, 32, 64);
            union { u32 u[4]; bf16x8 v; } bb;
            bb.u[0] = hs ? rcv0 : own0;
            bb.u[1] = hs ? rcv1 : own1;
            bb.u[2] = hs ? own0 : rcv0;
            bb.u[3] = hs ? own1 : rcv1;
            pf[seg] = bb.v;
        }

        #pragma unroll
        for (int ct = 0; ct < 8; ++ct) {
            const int c  = ct * 32 + li;
            const int rc = c >> 1;
            const int x  = rc & 15;
            const u16* vr = vb + rc * 64;
            const int cb = (c & 1) * 8 + hs * 2;
            #pragma unroll
            for (int seg = 0; seg < 2; ++seg) {
                const int q8  = cb + seg * 4;
                const int ch0 = q8 ^ x;
                const int ch1 = (q8 + 1) ^ x;
                union { uint2 g[2]; bf16x8 v8; } u;
                u.g[0] = *(const uint2*)(vr + ch0 * 4);
                u.g[1] = *(const uint2*)(vr + ch1 * 4);
                oacc[ct] = __builtin_amdgcn_mfma_f32_32x32x16_bf16(u.v8, pf[seg], oacc[ct], 0, 0, 0);
            }
        }
        __syncthreads();
    }

    ssl += __shfl_xor(ssl, 32, 64);
    if (hs == 0) sbuf[((size_t)h * BS + b) * NPIX + iw] = ssl;

    float* op = h ? opart1 : opart0;
    #pragma unroll
    for (int ct = 0; ct < 8; ++ct) {
        #pragma unroll
        for (int r = 0; r < 16; ++r) {
            const int c = ct * 32 + (r & 3) + 8 * (r >> 2) + 4 * hs;
            op[((size_t)b * C + c) * NPIX + iw] = oacc[ct][r];
        }
    }
}

// ---- merge: out = (O1+O2)/(s1+s2); fuse = out*motion -----------------------
__global__ __launch_bounds__(256)
void attn_merge(float* __restrict__ fuse,    // in: O1 partial, out: fuse_out
                float* __restrict__ outp,    // in: O2 partial, out: out
                const float* __restrict__ motion,
                const float* __restrict__ sbuf) {
    const size_t idx = ((size_t)blockIdx.x * 256 + threadIdx.x) * 4;
    const int n = (int)(idx & (NPIX - 1));
    const int b = (int)(idx >> 20);
    const float4 o1 = *(const float4*)(fuse + idx);
    const float4 o2 = *(const float4*)(outp + idx);
    const float4 sa = *(const float4*)(sbuf + (size_t)b * NPIX + n);
    const float4 sb = *(const float4*)(sbuf + (size_t)(BS + b) * NPIX + n);
    float4 o;
    o.x = (o1.x + o2.x) / (sa.x + sb.x);
    o.y = (o1.y + o2.y) / (sa.y + sb.y);
    o.z = (o1.z + o2.z) / (sa.z + sb.z);
    o.w = (o1.w + o2.w) / (sa.w + sb.w);
    const float4 mv = *(const float4*)(motion + idx);
    *(float4*)(outp + idx) = o;
    *(float4*)(fuse + idx) = make_float4(o.x * mv.x, o.y * mv.y, o.z * mv.z, o.w * mv.w);
}

extern "C" void kernel_launch(void* const* d_in, const int* in_sizes, int n_in,
                              void* d_out, int out_size, void* d_ws, size_t ws_size,
                              hipStream_t stream) {
    const float* a1     = (const float*)d_in[0];  // appearance_1 -> k
    const float* a2     = (const float*)d_in[1];  // appearance_2 -> q
    const float* motion = (const float*)d_in[2];  // -> v, and fuse multiplier
    const float* Wq = (const float*)d_in[3];
    const float* bq = (const float*)d_in[4];
    const float* Wk = (const float*)d_in[5];
    const float* bk = (const float*)d_in[6];
    const float* Wv = (const float*)d_in[7];
    const float* bv = (const float*)d_in[8];

    float* outp = (float*)d_out;  // [fuse_out | out]
    float* slot0 = outp;                              // fuse slot / O1 partial
    float* slot1 = outp + (size_t)BS * C * NPIX;      // out slot  / O2 partial

    // workspace: QT (8MB) | KT (8MB) | V (16MB) | sbuf (256KB) | W splits (384KB)
    u16* qws = (u16*)d_ws;
    u16* kws = qws + (size_t)BS * C2 * NPIX;
    u16* vws = kws + (size_t)BS * C2 * NPIX;
    float* sbuf = (float*)(vws + (size_t)BS * C * NPIX);
    u16* wqh = (u16*)(sbuf + (size_t)2 * BS * NPIX);
    u16* wql = wqh + C2 * C2;
    u16* wkh = wql + C2 * C2;
    u16* wkl = wkh + C2 * C2;
    u16* wvh = wkl + C2 * C2;
    u16* wvl = wvh + C * C;

    const dim3 blk(256);
    prep_w<<<dim3(32, 3), blk, 0, stream>>>(Wq, Wk, Wv, wqh, wql, wkh, wkl, wvh, wvl);
    proj_qk2<<<dim3(NPIX / 64, BS, 2), blk, 0, stream>>>(
        wqh, wql, bq, wkh, wkl, bk, a2, a1, qws, kws);
    proj_v2<<<dim3(NPIX / 64, BS), blk, 0, stream>>>(wvh, wvl, bv, motion, vws);

    attn_mfma3<<<dim3(512), blk, 0, stream>>>(qws, kws, vws, slot0, slot1, sbuf);

    attn_merge<<<dim3((BS * C * NPIX) / 1024), blk, 0, stream>>>(
        slot0, slot1, motion, sbuf);
}

// Round 3
// 302.330 us; speedup vs baseline: 1.2987x; 1.0905x over previous
//
#include <hip/hip_runtime.h>
#include <cstdint>
#include <cstddef>

#define BS   8
#define C    256
#define C2   128
#define NPIX 4096

typedef unsigned short u16;
typedef unsigned int   u32;
typedef __bf16 bf16_t;
typedef bf16_t bf16x8 __attribute__((ext_vector_type(8)));
typedef float  f32x16 __attribute__((ext_vector_type(16)));

__device__ __forceinline__ u16 f2bf(float f) {
    union { float ff; u32 i; } x; x.ff = f;
    u32 r = x.i + 0x7fffu + ((x.i >> 16) & 1u);  // RNE
    return (u16)(r >> 16);
}
__device__ __forceinline__ float bf2f(u16 h) {
    union { u32 i; float f; } x; x.i = (u32)h << 16; return x.f;
}
__device__ __forceinline__ u32 pk2(u16 a, u16 b) { return (u32)a | ((u32)b << 16); }

// ---------------- W pre-split: fragment-major hi/lo ------------------------
// W[o][c] fp32 -> Wh/Wl[c8*O + o][8] bf16.  W = Wh + Wl exact to ~2^-17.
__global__ __launch_bounds__(256)
void prep_w(const float* __restrict__ Wq, const float* __restrict__ Wk,
            const float* __restrict__ Wv,
            u16* __restrict__ qh, u16* __restrict__ ql,
            u16* __restrict__ kh, u16* __restrict__ kl,
            u16* __restrict__ vh, u16* __restrict__ vl) {
    const int z = blockIdx.y;                       // 0=q 1=k 2=v
    const int O = (z == 2) ? C : C2;                // O == CIN
    const int npair = O * O / 8;
    const int idx = blockIdx.x * 256 + threadIdx.x;
    if (idx >= npair) return;
    const int o  = idx & (O - 1);
    const int c8 = idx >> ((z == 2) ? 8 : 7);
    const float* src = (z == 0) ? Wq : (z == 1) ? Wk : Wv;
    u16* oh = (z == 0) ? qh : (z == 1) ? kh : vh;
    u16* ol = (z == 0) ? ql : (z == 1) ? kl : vl;
    u16 h[8], l[8];
    #pragma unroll
    for (int j = 0; j < 8; ++j) {
        const float f = src[(size_t)o * O + c8 * 8 + j];
        h[j] = f2bf(f);
        l[j] = f2bf(f - bf2f(h[j]));
    }
    *(uint4*)(oh + (size_t)idx * 8) =
        make_uint4(pk2(h[0], h[1]), pk2(h[2], h[3]), pk2(h[4], h[5]), pk2(h[6], h[7]));
    *(uint4*)(ol + (size_t)idx * 8) =
        make_uint4(pk2(l[0], l[1]), pk2(l[2], l[3]), pk2(l[4], l[5]), pk2(l[6], l[7]));
}

// ---------------- fused projections: z=0 Q, z=1 K, z=2/3 V n-halves --------
// 2-term: D = Wh*Xrne + Wl*Xrne (fp32 accum). X staged once (RNE bf16) into
// 16KB LDS, one barrier, then pure ds_read_b128 + MFMA.
__global__ __launch_bounds__(256, 4)
void proj_all(const u16* __restrict__ wqh, const u16* __restrict__ wql,
              const u16* __restrict__ wkh, const u16* __restrict__ wkl,
              const u16* __restrict__ wvh, const u16* __restrict__ wvl,
              const float* __restrict__ bq, const float* __restrict__ bk,
              const float* __restrict__ bv,
              const float* __restrict__ a2, const float* __restrict__ a1,
              const float* __restrict__ motion,
              u16* __restrict__ qout, u16* __restrict__ kout,
              u16* __restrict__ vout) {
    __shared__ __align__(16) u16 Xb[16][64][8];   // 16 KB (V path: [32][32][8])
    const int t  = threadIdx.x;
    const int w  = t >> 6;
    const int li = t & 31;
    const int hs = (t >> 5) & 1;
    const int z  = blockIdx.z;
    const int b  = blockIdx.y;

    if (z < 2) {
        // ---------------- Q / K : out [b][n][128] --------------------------
        const u16* wh = z ? wkh : wqh;
        const u16* wl = z ? wkl : wql;
        const float* bias = z ? bk : bq;
        const float* x    = z ? a1 : a2;
        u16* out          = z ? kout : qout;
        const int n0 = blockIdx.x * 64;
        {
            const int sn = t & 63;
            const float* xb = x + (size_t)b * C2 * NPIX + n0 + sn;
            #pragma unroll
            for (int q = 0; q < 4; ++q) {
                const int c8 = q * 4 + w;
                union { bf16_t e[8]; uint4 u4; } cv;
                #pragma unroll
                for (int j = 0; j < 8; ++j)
                    cv.e[j] = (bf16_t)xb[(size_t)(c8 * 8 + j) * NPIX];
                *(uint4*)&Xb[c8][sn][0] = cv.u4;
            }
        }
        __syncthreads();

        f32x16 acc[2];
        #pragma unroll
        for (int nt = 0; nt < 2; ++nt)
            #pragma unroll
            for (int e = 0; e < 16; ++e) acc[nt][e] = 0.f;

        const int ob = w * 32 + li;   // output channel (D col)
        #pragma unroll
        for (int ks = 0; ks < 8; ++ks) {
            const int c8 = ks * 2 + hs;
            const bf16x8 bh = *(const bf16x8*)(wh + ((size_t)c8 * C2 + ob) * 8);
            const bf16x8 bl = *(const bf16x8*)(wl + ((size_t)c8 * C2 + ob) * 8);
            #pragma unroll
            for (int nt = 0; nt < 2; ++nt) {
                const bf16x8 a = *(const bf16x8*)&Xb[c8][nt * 32 + li][0];
                acc[nt] = __builtin_amdgcn_mfma_f32_32x32x16_bf16(a, bh, acc[nt], 0, 0, 0);
                acc[nt] = __builtin_amdgcn_mfma_f32_32x32x16_bf16(a, bl, acc[nt], 0, 0, 0);
            }
        }

        const float bb = bias[ob];
        #pragma unroll
        for (int nt = 0; nt < 2; ++nt)
            #pragma unroll
            for (int r = 0; r < 16; ++r) {
                const int n = n0 + nt * 32 + (r & 3) + 8 * (r >> 2) + 4 * hs;
                out[((size_t)b * NPIX + n) * C2 + ob] = f2bf(acc[nt][r] + bb);
            }
    } else {
        // ---------------- V : out [b][o][n], n-tile 32 ---------------------
        u16 (*Xv)[32][8] = (u16 (*)[32][8])(&Xb[0][0][0]);
        const int n0 = blockIdx.x * 64 + (z - 2) * 32;
        {
            const int sn = t & 31;
            const int cg = t >> 5;
            const float* xb = motion + (size_t)b * C * NPIX + n0 + sn;
            #pragma unroll
            for (int r = 0; r < 4; ++r) {
                const int c8 = r * 8 + cg;
                union { bf16_t e[8]; uint4 u4; } cv;
                #pragma unroll
                for (int j = 0; j < 8; ++j)
                    cv.e[j] = (bf16_t)xb[(size_t)(c8 * 8 + j) * NPIX];
                *(uint4*)&Xv[c8][sn][0] = cv.u4;
            }
        }
        __syncthreads();

        f32x16 acc[2];
        #pragma unroll
        for (int ot = 0; ot < 2; ++ot)
            #pragma unroll
            for (int e = 0; e < 16; ++e) acc[ot][e] = 0.f;

        #pragma unroll
        for (int ks = 0; ks < 16; ++ks) {
            const int c8 = ks * 2 + hs;
            const bf16x8 xf = *(const bf16x8*)&Xv[c8][li][0];
            #pragma unroll
            for (int ot = 0; ot < 2; ++ot) {
                const int o = w * 64 + ot * 32 + li;
                const bf16x8 ah = *(const bf16x8*)(wvh + ((size_t)c8 * C + o) * 8);
                const bf16x8 al = *(const bf16x8*)(wvl + ((size_t)c8 * C + o) * 8);
                acc[ot] = __builtin_amdgcn_mfma_f32_32x32x16_bf16(ah, xf, acc[ot], 0, 0, 0);
                acc[ot] = __builtin_amdgcn_mfma_f32_32x32x16_bf16(al, xf, acc[ot], 0, 0, 0);
            }
        }

        #pragma unroll
        for (int ot = 0; ot < 2; ++ot)
            #pragma unroll
            for (int g = 0; g < 4; ++g) {
                const int orow = w * 64 + ot * 32 + 8 * g + 4 * hs;
                const float4 b4 = *(const float4*)&bv[orow];
                const size_t base = ((size_t)b * C + orow) * NPIX + n0 + li;
                vout[base]            = f2bf(acc[ot][g * 4 + 0] + b4.x);
                vout[base + NPIX]     = f2bf(acc[ot][g * 4 + 1] + b4.y);
                vout[base + 2 * NPIX] = f2bf(acc[ot][g * 4 + 2] + b4.z);
                vout[base + 3 * NPIX] = f2bf(acc[ot][g * 4 + 3] + b4.w);
            }
    }
}

// ----------------------------- MFMA attention v3 ---------------------------
struct SR { uint4 k[2]; uint4 v[4]; };

__device__ __forceinline__ void stg_load(const u16* __restrict__ kg,
                                         const u16* __restrict__ vg,
                                         int jt, int t, SR& R) {
    const u16* kp = kg + (size_t)jt * 32 * 128;
    #pragma unroll
    for (int q = 0; q < 2; ++q)
        R.k[q] = *(const uint4*)(kp + (size_t)(t + 256 * q) * 8);
    const u16* vp = vg + jt * 32 + (t & 3) * 8;
    #pragma unroll
    for (int q = 0; q < 4; ++q)
        R.v[q] = *(const uint4*)(vp + (size_t)((t >> 2) + 64 * q) * NPIX);
}

__device__ __forceinline__ void stg_write(u16* __restrict__ kb, u16* __restrict__ vb,
                                          int t, const SR& R) {
    #pragma unroll
    for (int q = 0; q < 2; ++q) {
        const int idx = t + 256 * q;
        const int row = idx >> 4;
        const int ch  = (idx & 15) ^ (row & 15);
        *(uint4*)(kb + row * 128 + ch * 8) = R.k[q];
    }
    #pragma unroll
    for (int q = 0; q < 4; ++q) {
        const int c   = (t >> 2) + 64 * q;
        const int rc  = c >> 1;
        const int q8  = (c & 1) * 8 + (t & 3) * 2;
        const int x   = rc & 15;
        const int ch0 = q8 ^ x;
        const int ch1 = (q8 + 1) ^ x;
        *(uint2*)(vb + rc * 64 + ch0 * 4) = make_uint2(R.v[q].x, R.v[q].y);
        *(uint2*)(vb + rc * 64 + ch1 * 4) = make_uint2(R.v[q].z, R.v[q].w);
    }
}

__global__ __launch_bounds__(256, 2)
void attn_mfma3(const u16* __restrict__ qt,   // [BS][NPIX][C2]
                const u16* __restrict__ kt,   // [BS][NPIX][C2]
                const u16* __restrict__ vn,   // [BS][C][NPIX]
                float* __restrict__ opart0,   // partial O, j-half 0 (fuse slot)
                float* __restrict__ opart1,   // partial O, j-half 1 (out slot)
                float* __restrict__ sbuf) {   // [2][BS][NPIX] partial sums
    __shared__ u16 Kb[2][32 * 128];
    __shared__ u16 Vb[2][128 * 64];

    const int t  = threadIdx.x;
    const int w  = t >> 6;
    const int li = t & 31;
    const int hs = (t >> 5) & 1;

    const int b  = blockIdx.x & 7;                 // batch <-> XCD affinity
    const int it = (blockIdx.x >> 3) & 31;
    const int h  = blockIdx.x >> 8;                // j-half
    const int i0 = it * 128;
    const int iw = i0 + w * 32 + li;
    const int j0 = h * 2048;

    bf16x8 qf[8];
    {
        const u16* qp = qt + ((size_t)b * NPIX + iw) * C2 + hs * 8;
        #pragma unroll
        for (int ct = 0; ct < 8; ++ct) qf[ct] = *(const bf16x8*)(qp + ct * 16);
    }

    f32x16 oacc[8];
    #pragma unroll
    for (int ct = 0; ct < 8; ++ct)
        #pragma unroll
        for (int e = 0; e < 16; ++e) oacc[ct][e] = 0.f;

    const u16* ktb = kt + ((size_t)b * NPIX + j0) * C2;
    const u16* vnb = vn + (size_t)b * C * NPIX + j0;

    SR R;
    stg_load(ktb, vnb, 0, t, R);
    stg_write(&Kb[0][0], &Vb[0][0], t, R);
    stg_load(ktb, vnb, 1, t, R);
    __syncthreads();

    float ssl = 0.f;
    for (int itr = 0; itr < 64; ++itr) {
        const int cur = itr & 1;
        if (itr < 63) {
            stg_write(&Kb[cur ^ 1][0], &Vb[cur ^ 1][0], t, R);
            if (itr < 62) stg_load(ktb, vnb, itr + 2, t, R);
        }
        const u16* kb = &Kb[cur][0];
        const u16* vb = &Vb[cur][0];

        // ---- S' = K Q^T  [32j x 32i]
        f32x16 s;
        #pragma unroll
        for (int e = 0; e < 16; ++e) s[e] = 0.f;
        {
            const int xr = li & 15;
            __builtin_amdgcn_s_setprio(1);
            #pragma unroll
            for (int ct = 0; ct < 8; ++ct) {
                const int ch = (ct * 2 + hs) ^ xr;
                const bf16x8 kf = *(const bf16x8*)(kb + li * 128 + ch * 8);
                s = __builtin_amdgcn_mfma_f32_32x32x16_bf16(kf, qf[ct], s, 0, 0, 0);
            }
            __builtin_amdgcn_s_setprio(0);
        }

        // ---- P = exp(S'), partial sums, pack bf16 pairs (native cvt)
        u32 pk[8];
        #pragma unroll
        for (int n = 0; n < 8; ++n) {
            const float p0 = __expf(s[2 * n]);
            const float p1 = __expf(s[2 * n + 1]);
            ssl += p0 + p1;
            union { bf16_t e[2]; u32 u; } cv;
            cv.e[0] = (bf16_t)p0;
            cv.e[1] = (bf16_t)p1;
            pk[n] = cv.u;
        }

        // ---- P' -> PV B-fragments via half-swap shuffle
        bf16x8 pf[2];
        #pragma unroll
        for (int seg = 0; seg < 2; ++seg) {
            const u32 A0 = pk[4 * seg + 0], A1 = pk[4 * seg + 1];
            const u32 A2 = pk[4 * seg + 2], A3 = pk[4 * seg + 3];
            const u32 own0 = hs ? A2 : A0, own1 = hs ? A3 : A1;
            const u32 snd0 = hs ? A0 : A2, snd1 = hs ? A1 : A3;
            const u32 rcv0 = (u32)__shfl_xor((int)snd0, 32, 64);
            const u32 rcv1 = (u32)__shfl_xor((int)snd1, 32, 64);
            union { u32 u[4]; bf16x8 v; } bb;
            bb.u[0] = hs ? rcv0 : own0;
            bb.u[1] = hs ? rcv1 : own1;
            bb.u[2] = hs ? own0 : rcv0;
            bb.u[3] = hs ? own1 : rcv1;
            pf[seg] = bb.v;
        }

        // ---- O += V P'
        __builtin_amdgcn_s_setprio(1);
        #pragma unroll
        for (int ct = 0; ct < 8; ++ct) {
            const int c  = ct * 32 + li;
            const int rc = c >> 1;
            const int x  = rc & 15;
            const u16* vr = vb + rc * 64;
            const int cb = (c & 1) * 8 + hs * 2;
            #pragma unroll
            for (int seg = 0; seg < 2; ++seg) {
                const int q8  = cb + seg * 4;
                const int ch0 = q8 ^ x;
                const int ch1 = (q8 + 1) ^ x;
                union { uint2 g[2]; bf16x8 v8; } u;
                u.g[0] = *(const uint2*)(vr + ch0 * 4);
                u.g[1] = *(const uint2*)(vr + ch1 * 4);
                oacc[ct] = __builtin_amdgcn_mfma_f32_32x32x16_bf16(u.v8, pf[seg], oacc[ct], 0, 0, 0);
            }
        }
        __builtin_amdgcn_s_setprio(0);
        __syncthreads();
    }

    ssl += __shfl_xor(ssl, 32, 64);
    if (hs == 0) sbuf[((size_t)h * BS + b) * NPIX + iw] = ssl;

    float* op = h ? opart1 : opart0;
    #pragma unroll
    for (int ct = 0; ct < 8; ++ct) {
        #pragma unroll
        for (int r = 0; r < 16; ++r) {
            const int c = ct * 32 + (r & 3) + 8 * (r >> 2) + 4 * hs;
            op[((size_t)b * C + c) * NPIX + iw] = oacc[ct][r];
        }
    }
}

// ---- merge: out = (O1+O2)/(s1+s2); fuse = out*motion -----------------------
__global__ __launch_bounds__(256)
void attn_merge(float* __restrict__ fuse,    // in: O1 partial, out: fuse_out
                float* __restrict__ outp,    // in: O2 partial, out: out
                const float* __restrict__ motion,
                const float* __restrict__ sbuf) {
    const size_t idx = ((size_t)blockIdx.x * 256 + threadIdx.x) * 4;
    const int n = (int)(idx & (NPIX - 1));
    const int b = (int)(idx >> 20);
    const float4 o1 = *(const float4*)(fuse + idx);
    const float4 o2 = *(const float4*)(outp + idx);
    const float4 sa = *(const float4*)(sbuf + (size_t)b * NPIX + n);
    const float4 sb = *(const float4*)(sbuf + (size_t)(BS + b) * NPIX + n);
    float4 o;
    o.x = (o1.x + o2.x) / (sa.x + sb.x);
    o.y = (o1.y + o2.y) / (sa.y + sb.y);
    o.z = (o1.z + o2.z) / (sa.z + sb.z);
    o.w = (o1.w + o2.w) / (sa.w + sb.w);
    const float4 mv = *(const float4*)(motion + idx);
    *(float4*)(outp + idx) = o;
    *(float4*)(fuse + idx) = make_float4(o.x * mv.x, o.y * mv.y, o.z * mv.z, o.w * mv.w);
}

extern "C" void kernel_launch(void* const* d_in, const int* in_sizes, int n_in,
                              void* d_out, int out_size, void* d_ws, size_t ws_size,
                              hipStream_t stream) {
    const float* a1     = (const float*)d_in[0];  // appearance_1 -> k
    const float* a2     = (const float*)d_in[1];  // appearance_2 -> q
    const float* motion = (const float*)d_in[2];  // -> v, and fuse multiplier
    const float* Wq = (const float*)d_in[3];
    const float* bq = (const float*)d_in[4];
    const float* Wk = (const float*)d_in[5];
    const float* bk = (const float*)d_in[6];
    const float* Wv = (const float*)d_in[7];
    const float* bv = (const float*)d_in[8];

    float* outp = (float*)d_out;  // [fuse_out | out]
    float* slot0 = outp;                              // fuse slot / O1 partial
    float* slot1 = outp + (size_t)BS * C * NPIX;      // out slot  / O2 partial

    // workspace: QT (8MB) | KT (8MB) | V (16MB) | sbuf (256KB) | W frags
    u16* qws = (u16*)d_ws;
    u16* kws = qws + (size_t)BS * C2 * NPIX;
    u16* vws = kws + (size_t)BS * C2 * NPIX;
    float* sbuf = (float*)(vws + (size_t)BS * C * NPIX);
    u16* wqh = (u16*)(sbuf + (size_t)2 * BS * NPIX);
    u16* wql = wqh + C2 * C2;
    u16* wkh = wql + C2 * C2;
    u16* wkl = wkh + C2 * C2;
    u16* wvh = wkl + C2 * C2;
    u16* wvl = wvh + C * C;

    const dim3 blk(256);
    prep_w<<<dim3(32, 3), blk, 0, stream>>>(Wq, Wk, Wv, wqh, wql, wkh, wkl, wvh, wvl);
    proj_all<<<dim3(NPIX / 64, BS, 4), blk, 0, stream>>>(
        wqh, wql, wkh, wkl, wvh, wvl, bq, bk, bv, a2, a1, motion, qws, kws, vws);

    attn_mfma3<<<dim3(512), blk, 0, stream>>>(qws, kws, vws, slot0, slot1, sbuf);

    attn_merge<<<dim3((BS * C * NPIX) / 1024), blk, 0, stream>>>(
        slot0, slot1, motion, sbuf);
}